// Round 11
// baseline (1118.386 us; speedup 1.0000x reference)
//
#include <hip/hip_runtime.h>
#include <hip/hip_bf16.h>

// GAT, 2 layers, N=8192 nodes, sparse adjacency (~270K edges incl. self-loops).
// Masked softmax with -1e9 fill == sparse neighbor softmax (exp underflows to 0).
// Round 11: SINGLE persistent mega-kernel (7 phases, 6 software grid barriers).
// Round-9 attribution showed ~37.5us of the 69us was inter-dispatch overhead
// (7 serialized graph nodes x ~5.4us flush/ramp). Grid=1024 blocks=4/CU
// co-resident (launch_bounds(256,4) caps VGPR<=128; 16KB LDS/block -> 64KB/CU).
// Barriers: release = __threadfence (buffer_wbl2, per-XCD L2 writeback) before
// atomic arrive; acquire = __threadfence in ALL threads after spin (buffer_inv)
// -- replicates the inter-kernel cache flush that XCD non-coherence requires.
// Counters zeroed per call via 64B hipMemsetAsync (capture-safe).
// Workspace (~26 MB + 64B ctr): same map as round 8, ctr at +26MB.

#define NN 8192
#define MAXD 128  // weight-phase slots; P(in-degree>128) ~ 1e-18 (Poisson 32)
#define GRID 1024

typedef __bf16 bf16x8 __attribute__((ext_vector_type(8)));
typedef float f32x4 __attribute__((ext_vector_type(4)));
typedef unsigned short u16x8 __attribute__((ext_vector_type(8)));

__device__ __forceinline__ unsigned short f2bf(float f) {
  unsigned u = __float_as_uint(f);
  unsigned r = (u + 0x7fffu + ((u >> 16) & 1u)) >> 16;  // round-nearest-even
  return (unsigned short)r;
}
__device__ __forceinline__ float bf2f(unsigned short u) {
  return __uint_as_float(((unsigned)u) << 16);
}
__device__ __forceinline__ float lrelu02(float e) { return e > 0.f ? e : 0.2f * e; }

// Software grid barrier. Deadlock-free iff all gridDim.x blocks co-resident
// (guaranteed: 1024 blocks = 4/CU at <=128 VGPR, 16KB LDS). Device-scope
// fences handle cross-XCD L2 non-coherence (wbl2 on release, inv on acquire).
__device__ __forceinline__ void grid_barrier(unsigned* __restrict__ ctr, int idx) {
  __syncthreads();
  if (threadIdx.x == 0) {
    __threadfence();  // release: write back this XCD's dirty L2 lines
    __hip_atomic_fetch_add(ctr + idx, 1u, __ATOMIC_ACQ_REL, __HIP_MEMORY_SCOPE_AGENT);
    while (__hip_atomic_load(ctr + idx, __ATOMIC_ACQUIRE, __HIP_MEMORY_SCOPE_AGENT) <
           gridDim.x)
      __builtin_amdgcn_s_sleep(1);
  }
  __syncthreads();
  __threadfence();  // acquire: invalidate L1/L2 in every wave before reads
}

__global__ __launch_bounds__(256, 4) void gat_mega_kernel(
    const float* __restrict__ X, const int* __restrict__ ei, const int E,
    const float* __restrict__ W1, const float* __restrict__ A1S,
    const float* __restrict__ A1D, const float* __restrict__ W2,
    const float* __restrict__ A2S, const float* __restrict__ A2D,
    unsigned short* __restrict__ h1b, unsigned short* __restrict__ out1b,
    unsigned* __restrict__ bitmap, float* __restrict__ f1s, float* __restrict__ f1d,
    float* __restrict__ h2, float* __restrict__ f2s, float* __restrict__ f2d,
    int* __restrict__ degarr, unsigned short* __restrict__ w1t,
    unsigned short* __restrict__ w2t, unsigned* __restrict__ ctr,
    float* __restrict__ out) {
  __shared__ __align__(16) unsigned char smem[16384];  // gemm1: 16KB; attn: 4KB
  const int tid = threadIdx.x;
  const int wv = tid >> 6, lane = tid & 63;
  const int lr = lane & 15, lg = lane >> 4;
  const int G = gridDim.x;
  const int gtid = blockIdx.x * 256 + tid;
  const int T = G * 256;
  const int gwave = blockIdx.x * 4 + wv;
  const int NW = G * 4;

  // ===== phase 0: zero bitmap + f1s/f1d, transpose W1/W2 to bf16 =====
  {
    uint4* b4 = (uint4*)bitmap;
    const uint4 z = {0u, 0u, 0u, 0u};
    for (int i = gtid; i < (NN * 256) / 4; i += T) b4[i] = z;
    for (int i = gtid; i < 256 * 512; i += T) {
      const int n = i >> 9, k = i & 511;
      w1t[i] = f2bf(W1[(size_t)k * 256 + n]);  // W1t[n][k]
    }
    for (int i = gtid; i < 16 * 256; i += T) {
      const int n = i >> 8, k = i & 255;
      w2t[i] = f2bf(W2[(size_t)k * 16 + n]);   // W2t[n][k]
    }
    float4* fz4 = (float4*)f1s;  // f1s ++ f1d contiguous: 4096 float4
    const float4 fz = {0.f, 0.f, 0.f, 0.f};
    for (int i = gtid; i < 4096; i += T) fz4[i] = fz;
  }
  grid_barrier(ctr, 0);

  // ===== phase 1: scatter edges into bitmap (device-scope atomicOr) =====
  for (int i = gtid; i < E; i += T) {
    const int s = ei[i];
    const int d = ei[E + i];
    atomicOr(bitmap + (size_t)s * 256 + (d >> 5), 1u << (d & 31));
  }
  grid_barrier(ctr, 1);

  // ===== phase 2: build CSR in place (one wave per row) =====
  for (int row = gwave; row < NN; row += NW) {
    unsigned* brow = bitmap + (size_t)row * 256;
    const uint4 wq = *(const uint4*)(brow + lane * 4);
    const int cnt = __popc(wq.x) + __popc(wq.y) + __popc(wq.z) + __popc(wq.w);
    int inc = cnt;
#pragma unroll
    for (int d = 1; d < 64; d <<= 1) {
      const int t2 = __shfl_up(inc, d);
      if (lane >= d) inc += t2;
    }
    int off = inc - cnt;  // exclusive prefix
    const int total = __shfl(inc, 63);
    unsigned short* nbp = (unsigned short*)brow;
    const unsigned words[4] = {wq.x, wq.y, wq.z, wq.w};
    const int base_j = lane * 128;
#pragma unroll
    for (int q = 0; q < 4; ++q) {
      unsigned word = words[q];
      while (word) {
        const int b = __ffs(word) - 1;
        word &= word - 1;
        nbp[off++] = (unsigned short)(base_j + q * 32 + b);
      }
    }
    if (lane == 0) degarr[row] = total;
  }
  grid_barrier(ctr, 2);

  // ===== phase 3: gemm1 (MFMA, 64x64 tile, XOR-swizzled LDS) + fused f1 =====
  // 512 tiles; blocks >=512 idle to the barrier. Same math as round 10.
  for (int tile = blockIdx.x; tile < 512; tile += G) {
    constexpr int K = 512;
    unsigned short* lds = (unsigned short*)smem;  // 512 A units + 512 B units
    const int bm = (tile >> 2) * 64, bn = (tile & 3) * 64;
    const int r8 = tid >> 3, c8 = tid & 7;
    f32x4 acc[4];
    const f32x4 fzv = {0.f, 0.f, 0.f, 0.f};
#pragma unroll
    for (int cb = 0; cb < 4; ++cb) acc[cb] = fzv;

    for (int k0 = 0; k0 < K; k0 += 64) {
      float4 xa[2][2];
#pragma unroll
      for (int p = 0; p < 2; ++p) {
        const float* s = X + (size_t)(bm + r8 + p * 32) * K + k0 + c8 * 8;
        xa[p][0] = *(const float4*)s;
        xa[p][1] = *(const float4*)(s + 4);
      }
      uint4 wb[2];
#pragma unroll
      for (int p = 0; p < 2; ++p)
        wb[p] = *(const uint4*)(w1t + (size_t)(bn + r8 + p * 32) * K + k0 + c8 * 8);
      __syncthreads();
#pragma unroll
      for (int p = 0; p < 2; ++p) {
        const int row = r8 + p * 32;
        const int u = ((row >> 4) << 7) + ((c8 >> 2) << 6) + ((c8 & 3) << 4) + ((row & 15) ^ c8);
        u16x8 v;
        v[0] = f2bf(xa[p][0].x); v[1] = f2bf(xa[p][0].y);
        v[2] = f2bf(xa[p][0].z); v[3] = f2bf(xa[p][0].w);
        v[4] = f2bf(xa[p][1].x); v[5] = f2bf(xa[p][1].y);
        v[6] = f2bf(xa[p][1].z); v[7] = f2bf(xa[p][1].w);
        *(u16x8*)(lds + u * 8) = v;
      }
#pragma unroll
      for (int p = 0; p < 2; ++p) {
        const int row = r8 + p * 32;
        const int u = 512 + ((row >> 4) << 7) + ((c8 >> 2) << 6) + ((c8 & 3) << 4) + ((row & 15) ^ c8);
        *(uint4*)(lds + u * 8) = wb[p];
      }
      __syncthreads();
#pragma unroll
      for (int ks = 0; ks < 2; ++ks) {
        const int xr = lr ^ (ks * 4 + lg);
        const bf16x8 a = *(const bf16x8*)(lds + ((wv << 7) + (ks << 6) + (lg << 4) + xr) * 8);
        const bf16x8 b0 = *(const bf16x8*)(lds + (512 + (0 << 7) + (ks << 6) + (lg << 4) + xr) * 8);
        const bf16x8 b1 = *(const bf16x8*)(lds + (512 + (1 << 7) + (ks << 6) + (lg << 4) + xr) * 8);
        const bf16x8 b2 = *(const bf16x8*)(lds + (512 + (2 << 7) + (ks << 6) + (lg << 4) + xr) * 8);
        const bf16x8 b3 = *(const bf16x8*)(lds + (512 + (3 << 7) + (ks << 6) + (lg << 4) + xr) * 8);
        acc[0] = __builtin_amdgcn_mfma_f32_16x16x32_bf16(a, b0, acc[0], 0, 0, 0);
        acc[1] = __builtin_amdgcn_mfma_f32_16x16x32_bf16(a, b1, acc[1], 0, 0, 0);
        acc[2] = __builtin_amdgcn_mfma_f32_16x16x32_bf16(a, b2, acc[2], 0, 0, 0);
        acc[3] = __builtin_amdgcn_mfma_f32_16x16x32_bf16(a, b3, acc[3], 0, 0, 0);
      }
    }
    // C-write; C/D layout: row=(l>>4)*4+q, col=l&15 (m89-verified)
#pragma unroll
    for (int cb = 0; cb < 4; ++cb)
#pragma unroll
      for (int q = 0; q < 4; ++q) {
        const int row = bm + wv * 16 + lg * 4 + q;
        h1b[(size_t)row * 256 + bn + cb * 16 + lr] = f2bf(acc[cb][q]);
      }
    // fused f1: partial dots over this tile's 64 cols, device-scope atomicAdd
    float a1sv[4], a1dv[4];
#pragma unroll
    for (int cb = 0; cb < 4; ++cb) {
      a1sv[cb] = A1S[bn + cb * 16 + lr];
      a1dv[cb] = A1D[bn + cb * 16 + lr];
    }
#pragma unroll
    for (int q = 0; q < 4; ++q) {
      float ps = 0.f, pd = 0.f;
#pragma unroll
      for (int cb = 0; cb < 4; ++cb) {
        ps = fmaf(acc[cb][q], a1sv[cb], ps);
        pd = fmaf(acc[cb][q], a1dv[cb], pd);
      }
#pragma unroll
      for (int off = 8; off; off >>= 1) {
        ps += __shfl_xor(ps, off, 16);
        pd += __shfl_xor(pd, off, 16);
      }
      if (lr == 0) {
        const int row = bm + wv * 16 + lg * 4 + q;
        atomicAdd(f1s + row, ps);
        atomicAdd(f1d + row, pd);
      }
    }
  }
  grid_barrier(ctr, 3);

  // ===== phase 4: layer-1 attention =====
  {
    float* wsh = (float*)smem;                 // [4][MAXD]
    int* jsh = (int*)(smem + 4 * MAXD * 4);    // [4][MAXD]
    for (int row = gwave; row < NN; row += NW) {
      const unsigned short* nbp = (const unsigned short*)(bitmap + (size_t)row * 256);
      const int deg = degarr[row];
      const float fsr = f1s[row];
      const int j0 = (lane < deg) ? (int)nbp[lane] : 0;
      const int j1 = (lane + 64 < deg) ? (int)nbp[lane + 64] : 0;
      const float e0 = (lane < deg) ? lrelu02(fsr + f1d[j0]) : -1e30f;
      const float e1 = (lane + 64 < deg) ? lrelu02(fsr + f1d[j1]) : -1e30f;
      float m = fmaxf(e0, e1);
#pragma unroll
      for (int off = 32; off; off >>= 1) m = fmaxf(m, __shfl_xor(m, off));
      const float w0 = (lane < deg) ? expf(e0 - m) : 0.f;
      const float w1 = (lane + 64 < deg) ? expf(e1 - m) : 0.f;
      float s = w0 + w1;
#pragma unroll
      for (int off = 32; off; off >>= 1) s += __shfl_xor(s, off);
      wsh[wv * MAXD + lane] = w0;
      jsh[wv * MAXD + lane] = j0;
      wsh[wv * MAXD + lane + 64] = w1;
      jsh[wv * MAXD + lane + 64] = j1;
      // gather: wave halves take alternating neighbors; 16B per lane
      const int half = lane >> 5, lh = lane & 31;
      float acc[8] = {0.f, 0.f, 0.f, 0.f, 0.f, 0.f, 0.f, 0.f};
      int t = 0;
      for (; t + 8 <= deg; t += 8) {
        const int ja = jsh[wv * MAXD + t + half], jb = jsh[wv * MAXD + t + 2 + half];
        const int jc = jsh[wv * MAXD + t + 4 + half], jd = jsh[wv * MAXD + t + 6 + half];
        const float Wa = wsh[wv * MAXD + t + half], Wb = wsh[wv * MAXD + t + 2 + half];
        const float Wc = wsh[wv * MAXD + t + 4 + half], Wd = wsh[wv * MAXD + t + 6 + half];
        const u16x8 va = *(const u16x8*)(h1b + (size_t)ja * 256 + lh * 8);
        const u16x8 vb = *(const u16x8*)(h1b + (size_t)jb * 256 + lh * 8);
        const u16x8 vc = *(const u16x8*)(h1b + (size_t)jc * 256 + lh * 8);
        const u16x8 vd = *(const u16x8*)(h1b + (size_t)jd * 256 + lh * 8);
#pragma unroll
        for (int e = 0; e < 8; ++e)
          acc[e] = fmaf(Wa, bf2f(va[e]),
                   fmaf(Wb, bf2f(vb[e]), fmaf(Wc, bf2f(vc[e]), fmaf(Wd, bf2f(vd[e]), acc[e]))));
      }
      for (; t < deg; t += 2) {
        const int idx = t + half;
        const int jt = (idx < deg) ? jsh[wv * MAXD + idx] : 0;
        const float Wt = (idx < deg) ? wsh[wv * MAXD + idx] : 0.f;
        const u16x8 v = *(const u16x8*)(h1b + (size_t)jt * 256 + lh * 8);
#pragma unroll
        for (int e = 0; e < 8; ++e) acc[e] = fmaf(Wt, bf2f(v[e]), acc[e]);
      }
#pragma unroll
      for (int e = 0; e < 8; ++e) acc[e] += __shfl_xor(acc[e], 32);
      const float inv = 1.f / s;
      u16x8 o;
#pragma unroll
      for (int e = 0; e < 8; ++e) {
        float v = acc[e] * inv;
        v = v > 0.f ? v : expf(v) - 1.f;  // elu
        o[e] = f2bf(v);
      }
      if (lane < 32) *(u16x8*)(out1b + (size_t)row * 256 + lh * 8) = o;
    }
  }
  grid_barrier(ctr, 4);

  // ===== phase 5: gemm2 (MFMA) + fused f2 (one wave per 16 rows) =====
  for (int job = gwave; job < NN / 16; job += NW) {
    const int row0 = job * 16;
    f32x4 acc = {0.f, 0.f, 0.f, 0.f};
#pragma unroll
    for (int k0 = 0; k0 < 256; k0 += 32) {
      const bf16x8 a = *(const bf16x8*)(out1b + (size_t)(row0 + lr) * 256 + k0 + lg * 8);
      const bf16x8 b = *(const bf16x8*)(w2t + (size_t)lr * 256 + k0 + lg * 8);
      acc = __builtin_amdgcn_mfma_f32_16x16x32_bf16(a, b, acc, 0, 0, 0);
    }
    const float as = A2S[lr], ad = A2D[lr];
#pragma unroll
    for (int q = 0; q < 4; ++q) {
      const int row = row0 + lg * 4 + q;  // C/D: row=(l>>4)*4+q, col=l&15
      const float v = acc[q];
      h2[(size_t)row * 16 + lr] = v;
      float ss = v * as, dd = v * ad;
#pragma unroll
      for (int off = 8; off; off >>= 1) {
        ss += __shfl_xor(ss, off, 16);
        dd += __shfl_xor(dd, off, 16);
      }
      if (lr == 0) {
        f2s[row] = ss;
        f2d[row] = dd;
      }
    }
  }
  grid_barrier(ctr, 5);

  // ===== phase 6: layer-2 attention + final log_softmax =====
  {
    float* wsh = (float*)smem;
    int* jsh = (int*)(smem + 4 * MAXD * 4);
    for (int row = gwave; row < NN; row += NW) {
      const unsigned short* nbp = (const unsigned short*)(bitmap + (size_t)row * 256);
      const int deg = degarr[row];
      const float fsr = f2s[row];
      const int j0 = (lane < deg) ? (int)nbp[lane] : 0;
      const int j1 = (lane + 64 < deg) ? (int)nbp[lane + 64] : 0;
      const float e0 = (lane < deg) ? lrelu02(fsr + f2d[j0]) : -1e30f;
      const float e1 = (lane + 64 < deg) ? lrelu02(fsr + f2d[j1]) : -1e30f;
      float m = fmaxf(e0, e1);
#pragma unroll
      for (int off = 32; off; off >>= 1) m = fmaxf(m, __shfl_xor(m, off));
      const float w0 = (lane < deg) ? expf(e0 - m) : 0.f;
      const float w1 = (lane + 64 < deg) ? expf(e1 - m) : 0.f;
      float s = w0 + w1;
#pragma unroll
      for (int off = 32; off; off >>= 1) s += __shfl_xor(s, off);
      wsh[wv * MAXD + lane] = w0;
      jsh[wv * MAXD + lane] = j0;
      wsh[wv * MAXD + lane + 64] = w1;
      jsh[wv * MAXD + lane + 64] = j1;
      const int c = lane & 15, g = lane >> 4;
      float acc = 0.f;
      int t = g;
      for (; t + 12 < deg; t += 16) {
        const float W0 = wsh[wv * MAXD + t], W1 = wsh[wv * MAXD + t + 4];
        const float W2 = wsh[wv * MAXD + t + 8], W3 = wsh[wv * MAXD + t + 12];
        const float v0 = h2[(size_t)jsh[wv * MAXD + t] * 16 + c];
        const float v1 = h2[(size_t)jsh[wv * MAXD + t + 4] * 16 + c];
        const float v2 = h2[(size_t)jsh[wv * MAXD + t + 8] * 16 + c];
        const float v3 = h2[(size_t)jsh[wv * MAXD + t + 12] * 16 + c];
        acc = fmaf(W0, v0, fmaf(W1, v1, fmaf(W2, v2, fmaf(W3, v3, acc))));
      }
      for (; t < deg; t += 4)
        acc = fmaf(wsh[wv * MAXD + t], h2[(size_t)jsh[wv * MAXD + t] * 16 + c], acc);
      acc += __shfl_xor(acc, 16);
      acc += __shfl_xor(acc, 32);
      const float v = acc / s;  // logits
      float mx = v;
#pragma unroll
      for (int off = 8; off; off >>= 1) mx = fmaxf(mx, __shfl_xor(mx, off, 16));
      float se = expf(v - mx);
#pragma unroll
      for (int off = 8; off; off >>= 1) se += __shfl_xor(se, off, 16);
      if (lane < 16) out[(size_t)row * 16 + lane] = v - mx - logf(se);
    }
  }
}

extern "C" void kernel_launch(void* const* d_in, const int* in_sizes, int n_in,
                              void* d_out, int out_size, void* d_ws, size_t ws_size,
                              hipStream_t stream) {
  const float* x = (const float*)d_in[0];
  const int* ei = (const int*)d_in[1];
  const float* W1 = (const float*)d_in[2];
  const float* a1s = (const float*)d_in[3];
  const float* a1d = (const float*)d_in[4];
  const float* W2 = (const float*)d_in[5];
  const float* a2s = (const float*)d_in[6];
  const float* a2d = (const float*)d_in[7];
  float* out = (float*)d_out;
  const int E = in_sizes[1] / 2;

  char* ws = (char*)d_ws;
  unsigned short* h1b = (unsigned short*)ws;                   // 4 MB
  unsigned short* out1b = (unsigned short*)(ws + (4u << 20));  // 4 MB
  unsigned* bitmap = (unsigned*)(ws + (16u << 20));            // 8 MB, reused as CSR
  float* f1s = (float*)(ws + (24u << 20));
  float* f1d = f1s + NN;
  float* h2 = f1d + NN;                                        // 512 KB
  float* f2s = h2 + (size_t)NN * 16;
  float* f2d = f2s + NN;
  int* deg = (int*)(f2d + NN);
  unsigned short* w1t = (unsigned short*)(deg + NN);           // 256 KB
  unsigned short* w2t = w1t + (size_t)256 * 512;               // 8 KB
  unsigned* ctr = (unsigned*)(ws + (26u << 20));               // 6 barrier counters

  hipMemsetAsync(ctr, 0, 64, stream);
  gat_mega_kernel<<<GRID, 256, 0, stream>>>(x, ei, E, W1, a1s, a1d, W2, a2s, a2d,
                                            h1b, out1b, bitmap, f1s, f1d, h2, f2s,
                                            f2d, deg, w1t, w2t, ctr, out);
}

// Round 12
// 917.002 us; speedup vs baseline: 1.2196x; 1.2196x over previous
//
#include <hip/hip_runtime.h>
#include <hip/hip_bf16.h>

// GAT, 2 layers, N=8192 nodes, sparse adjacency (~270K edges incl. self-loops).
// Masked softmax with -1e9 fill == sparse neighbor softmax (exp underflows to 0).
// Round 12: mega-kernel barrier FIX. Round 11's spin used agent-scope ACQUIRE
// loads -> buffer_inv (L1+L2 invalidate) EVERY spin iteration -> 1024 blocks
// storming the coherence fabric = 1118us with all pipes idle. Standard pattern:
// RELAXED spin + s_sleep backoff; synchronization via fences only (one wbl2
// release before arrive, one inv acquire per wave after exit).
// Workspace (~26 MB + 64B ctr): same map as round 8, ctr at +26MB.

#define NN 8192
#define MAXD 128  // weight-phase slots; P(in-degree>128) ~ 1e-18 (Poisson 32)
#define GRID 1024

typedef __bf16 bf16x8 __attribute__((ext_vector_type(8)));
typedef float f32x4 __attribute__((ext_vector_type(4)));
typedef unsigned short u16x8 __attribute__((ext_vector_type(8)));

__device__ __forceinline__ unsigned short f2bf(float f) {
  unsigned u = __float_as_uint(f);
  unsigned r = (u + 0x7fffu + ((u >> 16) & 1u)) >> 16;  // round-nearest-even
  return (unsigned short)r;
}
__device__ __forceinline__ float bf2f(unsigned short u) {
  return __uint_as_float(((unsigned)u) << 16);
}
__device__ __forceinline__ float lrelu02(float e) { return e > 0.f ? e : 0.2f * e; }

// Software grid barrier, cooperative-groups pattern. Deadlock-free iff all
// blocks co-resident (1024 blocks = 4/CU at <=128 VGPR, 16KB LDS; verified
// round 11: occupancy 49%, no hang). Synchronization via fence-to-fence:
// release __threadfence (buffer_wbl2) BEFORE relaxed arrive; RELAXED spin
// (plain coherent loads, NO per-iteration invalidate — round 11's bug was
// ACQUIRE spin loads emitting buffer_inv each iteration); acquire
// __threadfence (one buffer_inv per wave) after exit.
__device__ __forceinline__ void grid_barrier(unsigned* __restrict__ ctr, int idx) {
  __syncthreads();
  if (threadIdx.x == 0) {
    __threadfence();  // release: write back this XCD's dirty L2 lines
    __hip_atomic_fetch_add(ctr + idx, 1u, __ATOMIC_RELAXED, __HIP_MEMORY_SCOPE_AGENT);
    while (__hip_atomic_load(ctr + idx, __ATOMIC_RELAXED, __HIP_MEMORY_SCOPE_AGENT) <
           gridDim.x)
      __builtin_amdgcn_s_sleep(8);
  }
  __syncthreads();
  __threadfence();  // acquire: one L1/L2 invalidate per wave, then proceed
}

__global__ __launch_bounds__(256, 4) void gat_mega_kernel(
    const float* __restrict__ X, const int* __restrict__ ei, const int E,
    const float* __restrict__ W1, const float* __restrict__ A1S,
    const float* __restrict__ A1D, const float* __restrict__ W2,
    const float* __restrict__ A2S, const float* __restrict__ A2D,
    unsigned short* __restrict__ h1b, unsigned short* __restrict__ out1b,
    unsigned* __restrict__ bitmap, float* __restrict__ f1s, float* __restrict__ f1d,
    float* __restrict__ h2, float* __restrict__ f2s, float* __restrict__ f2d,
    int* __restrict__ degarr, unsigned short* __restrict__ w1t,
    unsigned short* __restrict__ w2t, unsigned* __restrict__ ctr,
    float* __restrict__ out) {
  __shared__ __align__(16) unsigned char smem[16384];  // gemm1: 16KB; attn: 4KB
  const int tid = threadIdx.x;
  const int wv = tid >> 6, lane = tid & 63;
  const int lr = lane & 15, lg = lane >> 4;
  const int G = gridDim.x;
  const int gtid = blockIdx.x * 256 + tid;
  const int T = G * 256;
  const int gwave = blockIdx.x * 4 + wv;
  const int NW = G * 4;

  // ===== phase 0: zero bitmap + f1s/f1d, transpose W1/W2 to bf16 =====
  {
    uint4* b4 = (uint4*)bitmap;
    const uint4 z = {0u, 0u, 0u, 0u};
    for (int i = gtid; i < (NN * 256) / 4; i += T) b4[i] = z;
    for (int i = gtid; i < 256 * 512; i += T) {
      const int n = i >> 9, k = i & 511;
      w1t[i] = f2bf(W1[(size_t)k * 256 + n]);  // W1t[n][k]
    }
    for (int i = gtid; i < 16 * 256; i += T) {
      const int n = i >> 8, k = i & 255;
      w2t[i] = f2bf(W2[(size_t)k * 16 + n]);   // W2t[n][k]
    }
    float4* fz4 = (float4*)f1s;  // f1s ++ f1d contiguous: 4096 float4
    const float4 fz = {0.f, 0.f, 0.f, 0.f};
    for (int i = gtid; i < 4096; i += T) fz4[i] = fz;
  }
  grid_barrier(ctr, 0);

  // ===== phase 1: scatter edges into bitmap (device-scope atomicOr) =====
  for (int i = gtid; i < E; i += T) {
    const int s = ei[i];
    const int d = ei[E + i];
    atomicOr(bitmap + (size_t)s * 256 + (d >> 5), 1u << (d & 31));
  }
  grid_barrier(ctr, 1);

  // ===== phase 2: build CSR in place (one wave per row) =====
  for (int row = gwave; row < NN; row += NW) {
    unsigned* brow = bitmap + (size_t)row * 256;
    const uint4 wq = *(const uint4*)(brow + lane * 4);
    const int cnt = __popc(wq.x) + __popc(wq.y) + __popc(wq.z) + __popc(wq.w);
    int inc = cnt;
#pragma unroll
    for (int d = 1; d < 64; d <<= 1) {
      const int t2 = __shfl_up(inc, d);
      if (lane >= d) inc += t2;
    }
    int off = inc - cnt;  // exclusive prefix
    const int total = __shfl(inc, 63);
    unsigned short* nbp = (unsigned short*)brow;
    const unsigned words[4] = {wq.x, wq.y, wq.z, wq.w};
    const int base_j = lane * 128;
#pragma unroll
    for (int q = 0; q < 4; ++q) {
      unsigned word = words[q];
      while (word) {
        const int b = __ffs(word) - 1;
        word &= word - 1;
        nbp[off++] = (unsigned short)(base_j + q * 32 + b);
      }
    }
    if (lane == 0) degarr[row] = total;
  }
  grid_barrier(ctr, 2);

  // ===== phase 3: gemm1 (MFMA, 64x64 tile, XOR-swizzled LDS) + fused f1 =====
  for (int tile = blockIdx.x; tile < 512; tile += G) {
    constexpr int K = 512;
    unsigned short* lds = (unsigned short*)smem;  // 512 A units + 512 B units
    const int bm = (tile >> 2) * 64, bn = (tile & 3) * 64;
    const int r8 = tid >> 3, c8 = tid & 7;
    f32x4 acc[4];
    const f32x4 fzv = {0.f, 0.f, 0.f, 0.f};
#pragma unroll
    for (int cb = 0; cb < 4; ++cb) acc[cb] = fzv;

    for (int k0 = 0; k0 < K; k0 += 64) {
      float4 xa[2][2];
#pragma unroll
      for (int p = 0; p < 2; ++p) {
        const float* s = X + (size_t)(bm + r8 + p * 32) * K + k0 + c8 * 8;
        xa[p][0] = *(const float4*)s;
        xa[p][1] = *(const float4*)(s + 4);
      }
      uint4 wb[2];
#pragma unroll
      for (int p = 0; p < 2; ++p)
        wb[p] = *(const uint4*)(w1t + (size_t)(bn + r8 + p * 32) * K + k0 + c8 * 8);
      __syncthreads();
#pragma unroll
      for (int p = 0; p < 2; ++p) {
        const int row = r8 + p * 32;
        const int u = ((row >> 4) << 7) + ((c8 >> 2) << 6) + ((c8 & 3) << 4) + ((row & 15) ^ c8);
        u16x8 v;
        v[0] = f2bf(xa[p][0].x); v[1] = f2bf(xa[p][0].y);
        v[2] = f2bf(xa[p][0].z); v[3] = f2bf(xa[p][0].w);
        v[4] = f2bf(xa[p][1].x); v[5] = f2bf(xa[p][1].y);
        v[6] = f2bf(xa[p][1].z); v[7] = f2bf(xa[p][1].w);
        *(u16x8*)(lds + u * 8) = v;
      }
#pragma unroll
      for (int p = 0; p < 2; ++p) {
        const int row = r8 + p * 32;
        const int u = 512 + ((row >> 4) << 7) + ((c8 >> 2) << 6) + ((c8 & 3) << 4) + ((row & 15) ^ c8);
        *(uint4*)(lds + u * 8) = wb[p];
      }
      __syncthreads();
#pragma unroll
      for (int ks = 0; ks < 2; ++ks) {
        const int xr = lr ^ (ks * 4 + lg);
        const bf16x8 a = *(const bf16x8*)(lds + ((wv << 7) + (ks << 6) + (lg << 4) + xr) * 8);
        const bf16x8 b0 = *(const bf16x8*)(lds + (512 + (0 << 7) + (ks << 6) + (lg << 4) + xr) * 8);
        const bf16x8 b1 = *(const bf16x8*)(lds + (512 + (1 << 7) + (ks << 6) + (lg << 4) + xr) * 8);
        const bf16x8 b2 = *(const bf16x8*)(lds + (512 + (2 << 7) + (ks << 6) + (lg << 4) + xr) * 8);
        const bf16x8 b3 = *(const bf16x8*)(lds + (512 + (3 << 7) + (ks << 6) + (lg << 4) + xr) * 8);
        acc[0] = __builtin_amdgcn_mfma_f32_16x16x32_bf16(a, b0, acc[0], 0, 0, 0);
        acc[1] = __builtin_amdgcn_mfma_f32_16x16x32_bf16(a, b1, acc[1], 0, 0, 0);
        acc[2] = __builtin_amdgcn_mfma_f32_16x16x32_bf16(a, b2, acc[2], 0, 0, 0);
        acc[3] = __builtin_amdgcn_mfma_f32_16x16x32_bf16(a, b3, acc[3], 0, 0, 0);
      }
    }
    // C-write; C/D layout: row=(l>>4)*4+q, col=l&15 (m89-verified)
#pragma unroll
    for (int cb = 0; cb < 4; ++cb)
#pragma unroll
      for (int q = 0; q < 4; ++q) {
        const int row = bm + wv * 16 + lg * 4 + q;
        h1b[(size_t)row * 256 + bn + cb * 16 + lr] = f2bf(acc[cb][q]);
      }
    // fused f1: partial dots over this tile's 64 cols, device-scope atomicAdd
    float a1sv[4], a1dv[4];
#pragma unroll
    for (int cb = 0; cb < 4; ++cb) {
      a1sv[cb] = A1S[bn + cb * 16 + lr];
      a1dv[cb] = A1D[bn + cb * 16 + lr];
    }
#pragma unroll
    for (int q = 0; q < 4; ++q) {
      float ps = 0.f, pd = 0.f;
#pragma unroll
      for (int cb = 0; cb < 4; ++cb) {
        ps = fmaf(acc[cb][q], a1sv[cb], ps);
        pd = fmaf(acc[cb][q], a1dv[cb], pd);
      }
#pragma unroll
      for (int off = 8; off; off >>= 1) {
        ps += __shfl_xor(ps, off, 16);
        pd += __shfl_xor(pd, off, 16);
      }
      if (lr == 0) {
        const int row = bm + wv * 16 + lg * 4 + q;
        atomicAdd(f1s + row, ps);
        atomicAdd(f1d + row, pd);
      }
    }
  }
  grid_barrier(ctr, 3);

  // ===== phase 4: layer-1 attention =====
  {
    float* wsh = (float*)smem;                 // [4][MAXD]
    int* jsh = (int*)(smem + 4 * MAXD * 4);    // [4][MAXD]
    for (int row = gwave; row < NN; row += NW) {
      const unsigned short* nbp = (const unsigned short*)(bitmap + (size_t)row * 256);
      const int deg = degarr[row];
      const float fsr = f1s[row];
      const int j0 = (lane < deg) ? (int)nbp[lane] : 0;
      const int j1 = (lane + 64 < deg) ? (int)nbp[lane + 64] : 0;
      const float e0 = (lane < deg) ? lrelu02(fsr + f1d[j0]) : -1e30f;
      const float e1 = (lane + 64 < deg) ? lrelu02(fsr + f1d[j1]) : -1e30f;
      float m = fmaxf(e0, e1);
#pragma unroll
      for (int off = 32; off; off >>= 1) m = fmaxf(m, __shfl_xor(m, off));
      const float w0 = (lane < deg) ? expf(e0 - m) : 0.f;
      const float w1 = (lane + 64 < deg) ? expf(e1 - m) : 0.f;
      float s = w0 + w1;
#pragma unroll
      for (int off = 32; off; off >>= 1) s += __shfl_xor(s, off);
      wsh[wv * MAXD + lane] = w0;
      jsh[wv * MAXD + lane] = j0;
      wsh[wv * MAXD + lane + 64] = w1;
      jsh[wv * MAXD + lane + 64] = j1;
      // gather: wave halves take alternating neighbors; 16B per lane
      const int half = lane >> 5, lh = lane & 31;
      float acc[8] = {0.f, 0.f, 0.f, 0.f, 0.f, 0.f, 0.f, 0.f};
      int t = 0;
      for (; t + 8 <= deg; t += 8) {
        const int ja = jsh[wv * MAXD + t + half], jb = jsh[wv * MAXD + t + 2 + half];
        const int jc = jsh[wv * MAXD + t + 4 + half], jd = jsh[wv * MAXD + t + 6 + half];
        const float Wa = wsh[wv * MAXD + t + half], Wb = wsh[wv * MAXD + t + 2 + half];
        const float Wc = wsh[wv * MAXD + t + 4 + half], Wd = wsh[wv * MAXD + t + 6 + half];
        const u16x8 va = *(const u16x8*)(h1b + (size_t)ja * 256 + lh * 8);
        const u16x8 vb = *(const u16x8*)(h1b + (size_t)jb * 256 + lh * 8);
        const u16x8 vc = *(const u16x8*)(h1b + (size_t)jc * 256 + lh * 8);
        const u16x8 vd = *(const u16x8*)(h1b + (size_t)jd * 256 + lh * 8);
#pragma unroll
        for (int e = 0; e < 8; ++e)
          acc[e] = fmaf(Wa, bf2f(va[e]),
                   fmaf(Wb, bf2f(vb[e]), fmaf(Wc, bf2f(vc[e]), fmaf(Wd, bf2f(vd[e]), acc[e]))));
      }
      for (; t < deg; t += 2) {
        const int idx = t + half;
        const int jt = (idx < deg) ? jsh[wv * MAXD + idx] : 0;
        const float Wt = (idx < deg) ? wsh[wv * MAXD + idx] : 0.f;
        const u16x8 v = *(const u16x8*)(h1b + (size_t)jt * 256 + lh * 8);
#pragma unroll
        for (int e = 0; e < 8; ++e) acc[e] = fmaf(Wt, bf2f(v[e]), acc[e]);
      }
#pragma unroll
      for (int e = 0; e < 8; ++e) acc[e] += __shfl_xor(acc[e], 32);
      const float inv = 1.f / s;
      u16x8 o;
#pragma unroll
      for (int e = 0; e < 8; ++e) {
        float v = acc[e] * inv;
        v = v > 0.f ? v : expf(v) - 1.f;  // elu
        o[e] = f2bf(v);
      }
      if (lane < 32) *(u16x8*)(out1b + (size_t)row * 256 + lh * 8) = o;
    }
  }
  grid_barrier(ctr, 4);

  // ===== phase 5: gemm2 (MFMA) + fused f2 (one wave per 16 rows) =====
  for (int job = gwave; job < NN / 16; job += NW) {
    const int row0 = job * 16;
    f32x4 acc = {0.f, 0.f, 0.f, 0.f};
#pragma unroll
    for (int k0 = 0; k0 < 256; k0 += 32) {
      const bf16x8 a = *(const bf16x8*)(out1b + (size_t)(row0 + lr) * 256 + k0 + lg * 8);
      const bf16x8 b = *(const bf16x8*)(w2t + (size_t)lr * 256 + k0 + lg * 8);
      acc = __builtin_amdgcn_mfma_f32_16x16x32_bf16(a, b, acc, 0, 0, 0);
    }
    const float as = A2S[lr], ad = A2D[lr];
#pragma unroll
    for (int q = 0; q < 4; ++q) {
      const int row = row0 + lg * 4 + q;  // C/D: row=(l>>4)*4+q, col=l&15
      const float v = acc[q];
      h2[(size_t)row * 16 + lr] = v;
      float ss = v * as, dd = v * ad;
#pragma unroll
      for (int off = 8; off; off >>= 1) {
        ss += __shfl_xor(ss, off, 16);
        dd += __shfl_xor(dd, off, 16);
      }
      if (lr == 0) {
        f2s[row] = ss;
        f2d[row] = dd;
      }
    }
  }
  grid_barrier(ctr, 5);

  // ===== phase 6: layer-2 attention + final log_softmax =====
  {
    float* wsh = (float*)smem;
    int* jsh = (int*)(smem + 4 * MAXD * 4);
    for (int row = gwave; row < NN; row += NW) {
      const unsigned short* nbp = (const unsigned short*)(bitmap + (size_t)row * 256);
      const int deg = degarr[row];
      const float fsr = f2s[row];
      const int j0 = (lane < deg) ? (int)nbp[lane] : 0;
      const int j1 = (lane + 64 < deg) ? (int)nbp[lane + 64] : 0;
      const float e0 = (lane < deg) ? lrelu02(fsr + f2d[j0]) : -1e30f;
      const float e1 = (lane + 64 < deg) ? lrelu02(fsr + f2d[j1]) : -1e30f;
      float m = fmaxf(e0, e1);
#pragma unroll
      for (int off = 32; off; off >>= 1) m = fmaxf(m, __shfl_xor(m, off));
      const float w0 = (lane < deg) ? expf(e0 - m) : 0.f;
      const float w1 = (lane + 64 < deg) ? expf(e1 - m) : 0.f;
      float s = w0 + w1;
#pragma unroll
      for (int off = 32; off; off >>= 1) s += __shfl_xor(s, off);
      wsh[wv * MAXD + lane] = w0;
      jsh[wv * MAXD + lane] = j0;
      wsh[wv * MAXD + lane + 64] = w1;
      jsh[wv * MAXD + lane + 64] = j1;
      const int c = lane & 15, g = lane >> 4;
      float acc = 0.f;
      int t = g;
      for (; t + 12 < deg; t += 16) {
        const float W0 = wsh[wv * MAXD + t], W1 = wsh[wv * MAXD + t + 4];
        const float W2 = wsh[wv * MAXD + t + 8], W3 = wsh[wv * MAXD + t + 12];
        const float v0 = h2[(size_t)jsh[wv * MAXD + t] * 16 + c];
        const float v1 = h2[(size_t)jsh[wv * MAXD + t + 4] * 16 + c];
        const float v2 = h2[(size_t)jsh[wv * MAXD + t + 8] * 16 + c];
        const float v3 = h2[(size_t)jsh[wv * MAXD + t + 12] * 16 + c];
        acc = fmaf(W0, v0, fmaf(W1, v1, fmaf(W2, v2, fmaf(W3, v3, acc))));
      }
      for (; t < deg; t += 4)
        acc = fmaf(wsh[wv * MAXD + t], h2[(size_t)jsh[wv * MAXD + t] * 16 + c], acc);
      acc += __shfl_xor(acc, 16);
      acc += __shfl_xor(acc, 32);
      const float v = acc / s;  // logits
      float mx = v;
#pragma unroll
      for (int off = 8; off; off >>= 1) mx = fmaxf(mx, __shfl_xor(mx, off, 16));
      float se = expf(v - mx);
#pragma unroll
      for (int off = 8; off; off >>= 1) se += __shfl_xor(se, off, 16);
      if (lane < 16) out[(size_t)row * 16 + lane] = v - mx - logf(se);
    }
  }
}

extern "C" void kernel_launch(void* const* d_in, const int* in_sizes, int n_in,
                              void* d_out, int out_size, void* d_ws, size_t ws_size,
                              hipStream_t stream) {
  const float* x = (const float*)d_in[0];
  const int* ei = (const int*)d_in[1];
  const float* W1 = (const float*)d_in[2];
  const float* a1s = (const float*)d_in[3];
  const float* a1d = (const float*)d_in[4];
  const float* W2 = (const float*)d_in[5];
  const float* a2s = (const float*)d_in[6];
  const float* a2d = (const float*)d_in[7];
  float* out = (float*)d_out;
  const int E = in_sizes[1] / 2;

  char* ws = (char*)d_ws;
  unsigned short* h1b = (unsigned short*)ws;                   // 4 MB
  unsigned short* out1b = (unsigned short*)(ws + (4u << 20));  // 4 MB
  unsigned* bitmap = (unsigned*)(ws + (16u << 20));            // 8 MB, reused as CSR
  float* f1s = (float*)(ws + (24u << 20));
  float* f1d = f1s + NN;
  float* h2 = f1d + NN;                                        // 512 KB
  float* f2s = h2 + (size_t)NN * 16;
  float* f2d = f2s + NN;
  int* deg = (int*)(f2d + NN);
  unsigned short* w1t = (unsigned short*)(deg + NN);           // 256 KB
  unsigned short* w2t = w1t + (size_t)256 * 512;               // 8 KB
  unsigned* ctr = (unsigned*)(ws + (26u << 20));               // 6 barrier counters

  hipMemsetAsync(ctr, 0, 64, stream);
  gat_mega_kernel<<<GRID, 256, 0, stream>>>(x, ei, E, W1, a1s, a1d, W2, a2s, a2d,
                                            h1b, out1b, bitmap, f1s, f1d, h2, f2s,
                                            f2d, deg, w1t, w2t, ctr, out);
}